// Round 1
// baseline (439.931 us; speedup 1.0000x reference)
//
#include <hip/hip_runtime.h>

// NonLocalBlock: B=4, C=256, Ci=128, H=W=64, N=4096.
// f16 MFMA (16x16x32) throughout; f (4096x4096 per batch) never materialized:
// pass2 computes column softmax stats (softmax over query axis), pass3
// recomputes f and applies exp(f-m)*rD before PV.

#define B_  4
#define C_  256
#define CI  128
#define N_  4096
#define NB  (B_*N_)     // 16384
#define ISPLIT 4

typedef _Float16 f16;
typedef f16   f16x8 __attribute__((ext_vector_type(8)));
typedef f16   f16x4 __attribute__((ext_vector_type(4)));
typedef float f32x4 __attribute__((ext_vector_type(4)));

#define MFMA(a,b,c) __builtin_amdgcn_mfma_f32_16x16x32_f16(a,b,c,0,0,0)

// ---- workspace byte offsets (need ~34 MB) ----
#define OFF_THETA  0                       // f16 [B][N][CI]  4 MB
#define OFF_PHI    (4u<<20)                // f16 [B][N][CI]  4 MB
#define OFF_G      (8u<<20)                // f16 [B][CI][N]  4 MB
#define OFF_Y      (12u<<20)               // f16 [B][N][CI]  4 MB
#define OFF_WY     (16u<<20)               // f32 [B][C][N]  16 MB
#define OFF_WCVT   (32u<<20)               // f16 weights: g,theta,phi [128*256] then wz [256*128]
#define OFF_PM     ((32u<<20) + (1u<<18))  // f32 [ISPLIT][NB]  256 KB
#define OFF_PS     (OFF_PM + (ISPLIT*NB*4))
#define OFF_M      (OFF_PS + (ISPLIT*NB*4))  // f32 [NB]
#define OFF_RD     (OFF_M + NB*4)            // f32 [NB]
#define OFF_SSUM   (OFF_RD + NB*4)           // f32 [256]
#define OFF_SSQ    (OFF_SSUM + 1024)
#define OFF_SC     (OFF_SSQ + 1024)
#define OFF_SH     (OFF_SC + 1024)

// ---------------- weight conversion f32 -> f16 ----------------
__global__ void k_prep(const float* gw, const float* tw, const float* pw,
                       const float* zw, f16* wcvt) {
    int i = blockIdx.x * 256 + threadIdx.x;          // 0..131071
    const float* s;
    int which = i >> 15;
    if (which == 0) s = gw; else if (which == 1) s = tw;
    else if (which == 2) s = pw; else s = zw;
    wcvt[i] = (f16)s[i & 32767];
}

// ---------------- fused 1x1-conv projections (MFMA) ----------------
// grid: (B*N/64, 3).  blockIdx.y: 0=g, 1=theta, 2=phi.
__global__ __launch_bounds__(256) void k_proj(
        const float* __restrict__ x, const f16* __restrict__ wcvt,
        const float* __restrict__ gb, const float* __restrict__ tb,
        const float* __restrict__ pb,
        f16* __restrict__ thetaT, f16* __restrict__ phiT, f16* __restrict__ gC) {
    __shared__ __align__(16) f16 xT[64 * 264];       // [n][c], stride 264
    int proj = blockIdx.y;
    int bb = blockIdx.x >> 6;
    int n0 = (blockIdx.x & 63) * 64;
    int t = threadIdx.x;

    const float* xb = x + (size_t)bb * C_ * N_;
    for (int rep = 0; rep < 16; rep++) {
        int lin = rep * 256 + t;
        int c = lin >> 4, np = (lin & 15) * 4;
        float4 v = *reinterpret_cast<const float4*>(xb + c * N_ + n0 + np);
        xT[(np + 0) * 264 + c] = (f16)v.x;
        xT[(np + 1) * 264 + c] = (f16)v.y;
        xT[(np + 2) * 264 + c] = (f16)v.z;
        xT[(np + 3) * 264 + c] = (f16)v.w;
    }
    __syncthreads();

    int w = t >> 6, l16 = t & 15, q = (t & 63) >> 4;
    const f16* W0 = wcvt + proj * 32768;             // [128][256] row-major
    int ci0 = w * 32;
    f32x4 acc[2][4] = {};
    for (int kk = 0; kk < 8; kk++) {
        f16x8 a0 = *reinterpret_cast<const f16x8*>(W0 + (ci0 + l16) * 256 + kk * 32 + q * 8);
        f16x8 a1 = *reinterpret_cast<const f16x8*>(W0 + (ci0 + 16 + l16) * 256 + kk * 32 + q * 8);
#pragma unroll
        for (int nt = 0; nt < 4; nt++) {
            f16x8 bv = *reinterpret_cast<const f16x8*>(&xT[(nt * 16 + l16) * 264 + kk * 32 + q * 8]);
            acc[0][nt] = MFMA(a0, bv, acc[0][nt]);
            acc[1][nt] = MFMA(a1, bv, acc[1][nt]);
        }
    }
    const float* bias = (proj == 0) ? gb : (proj == 1) ? tb : pb;
#pragma unroll
    for (int a = 0; a < 2; a++) {
#pragma unroll
        for (int nt = 0; nt < 4; nt++) {
            int n = n0 + nt * 16 + l16;
            int cib = ci0 + a * 16 + q * 4;
            if (proj == 0) {
#pragma unroll
                for (int r = 0; r < 4; r++)
                    gC[((size_t)bb * CI + cib + r) * N_ + n] = (f16)(acc[a][nt][r] + bias[cib + r]);
            } else {
                f16x4 v4;
#pragma unroll
                for (int r = 0; r < 4; r++) v4[r] = (f16)(acc[a][nt][r] + bias[cib + r]);
                f16* dst = (proj == 1 ? thetaT : phiT) + ((size_t)bb * N_ + n) * CI + cib;
                *reinterpret_cast<f16x4*>(dst) = v4;
            }
        }
    }
}

// ---------------- pass 2: column softmax stats ----------------
// One wave per (b, 32 j-cols, i-split of 1024). Online softmax over i.
__global__ __launch_bounds__(64) void k_cols(
        const f16* __restrict__ thetaT, const f16* __restrict__ phiT,
        float* __restrict__ pm, float* __restrict__ ps) {
    int id = blockIdx.x;                 // 2048
    int isp = id & 3;
    int jb = (id >> 2) & 127;
    int bb = id >> 9;
    int l = threadIdx.x, l16 = l & 15, q = l >> 4;
    int j0 = jb * 32;

    f16x8 pf[2][4];
#pragma unroll
    for (int jt = 0; jt < 2; jt++)
#pragma unroll
        for (int kk = 0; kk < 4; kk++)
            pf[jt][kk] = *reinterpret_cast<const f16x8*>(
                phiT + ((size_t)bb * N_ + j0 + jt * 16 + l16) * CI + kk * 32 + q * 8);

    float m0 = -__builtin_inff(), m1 = -__builtin_inff(), s0 = 0.f, s1 = 0.f;
    const f16* tbase = thetaT + ((size_t)bb * N_ + isp * 1024 + l16) * CI + q * 8;
    for (int ic = 0; ic < 64; ic++) {
        const f16* ta = tbase + (size_t)ic * 16 * CI;
        f32x4 f0 = {0,0,0,0}, f1 = {0,0,0,0};
#pragma unroll
        for (int kk = 0; kk < 4; kk++) {
            f16x8 av = *reinterpret_cast<const f16x8*>(ta + kk * 32);
            f0 = MFMA(av, pf[0][kk], f0);
            f1 = MFMA(av, pf[1][kk], f1);
        }
        float vm = fmaxf(fmaxf(f0[0], f0[1]), fmaxf(f0[2], f0[3]));
        float mn = fmaxf(m0, vm);
        s0 = s0 * __expf(m0 - mn) + __expf(f0[0]-mn) + __expf(f0[1]-mn) + __expf(f0[2]-mn) + __expf(f0[3]-mn);
        m0 = mn;
        vm = fmaxf(fmaxf(f1[0], f1[1]), fmaxf(f1[2], f1[3]));
        mn = fmaxf(m1, vm);
        s1 = s1 * __expf(m1 - mn) + __expf(f1[0]-mn) + __expf(f1[1]-mn) + __expf(f1[2]-mn) + __expf(f1[3]-mn);
        m1 = mn;
    }
#pragma unroll
    for (int off = 16; off < 64; off <<= 1) {
        float om = __shfl_xor(m0, off), os = __shfl_xor(s0, off);
        float mn = fmaxf(m0, om);
        s0 = s0 * __expf(m0 - mn) + os * __expf(om - mn); m0 = mn;
        om = __shfl_xor(m1, off); os = __shfl_xor(s1, off);
        mn = fmaxf(m1, om);
        s1 = s1 * __expf(m1 - mn) + os * __expf(om - mn); m1 = mn;
    }
    if (q == 0) {
        int base = isp * NB + bb * N_ + j0 + l16;
        pm[base] = m0;       ps[base] = s0;
        pm[base + 16] = m1;  ps[base + 16] = s1;
    }
}

__global__ void k_colmerge(const float* __restrict__ pm, const float* __restrict__ ps,
                           float* __restrict__ mcol, float* __restrict__ rdcol) {
    int j = blockIdx.x * 256 + threadIdx.x;          // 0..16383
    float m = pm[j];
    for (int isp = 1; isp < ISPLIT; isp++) m = fmaxf(m, pm[isp * NB + j]);
    float s = 0.f;
    for (int isp = 0; isp < ISPLIT; isp++) s += ps[isp * NB + j] * __expf(pm[isp * NB + j] - m);
    mcol[j] = m;
    rdcol[j] = 1.0f / s;
}

// ---------------- pass 3: y = softmax(f) @ g ----------------
// wg = 16 query rows (i), 4 waves split j-range; theta frags register-resident;
// W = exp(f-m)*rD transposed through per-wave LDS; y combined via LDS.
__global__ __launch_bounds__(256) void k_attn(
        const f16* __restrict__ thetaT, const f16* __restrict__ phiT,
        const f16* __restrict__ gC, const float* __restrict__ mcol,
        const float* __restrict__ rdcol, f16* __restrict__ yT) {
    __shared__ __align__(16) f16   Wl[4][16 * 40];    // per-wave [16 i][32 j] pad 8
    __shared__ __align__(16) float comb[4][16 * 132]; // per-wave [16 i][128 c] pad 4
    int bb = blockIdx.x >> 8;
    int i0 = (blockIdx.x & 255) * 16;
    int t = threadIdx.x, w = t >> 6, l16 = t & 15, q = (t & 63) >> 4;

    f16x8 ta[4];
#pragma unroll
    for (int kk = 0; kk < 4; kk++)
        ta[kk] = *reinterpret_cast<const f16x8*>(
            thetaT + ((size_t)bb * N_ + i0 + l16) * CI + kk * 32 + q * 8);

    f32x4 yacc[8] = {};
    const float* mb = mcol + bb * N_;
    const float* rb = rdcol + bb * N_;
    for (int jc = 0; jc < 32; jc++) {
        int j0 = w * 1024 + jc * 32;
#pragma unroll
        for (int jt = 0; jt < 2; jt++) {
            f32x4 f = {0,0,0,0};
#pragma unroll
            for (int kk = 0; kk < 4; kk++) {
                f16x8 pv = *reinterpret_cast<const f16x8*>(
                    phiT + ((size_t)bb * N_ + j0 + jt * 16 + l16) * CI + kk * 32 + q * 8);
                f = MFMA(ta[kk], pv, f);
            }
            float mj = mb[j0 + jt * 16 + l16];
            float rj = rb[j0 + jt * 16 + l16];
#pragma unroll
            for (int r = 0; r < 4; r++)
                Wl[w][(q * 4 + r) * 40 + jt * 16 + l16] = (f16)(__expf(f[r] - mj) * rj);
        }
        // same-wave LDS RAW: compiler inserts lgkmcnt wait; no barrier needed
        f16x8 wf = *reinterpret_cast<const f16x8*>(&Wl[w][l16 * 40 + q * 8]);
#pragma unroll
        for (int d = 0; d < 8; d++) {
            f16x8 gv = *reinterpret_cast<const f16x8*>(
                gC + ((size_t)bb * CI + d * 16 + l16) * N_ + j0 + q * 8);
            yacc[d] = MFMA(wf, gv, yacc[d]);
        }
    }
#pragma unroll
    for (int d = 0; d < 8; d++)
#pragma unroll
        for (int r = 0; r < 4; r++)
            comb[w][(q * 4 + r) * 132 + d * 16 + l16] = yacc[d][r];
    __syncthreads();
    int i = t >> 4, c0 = (t & 15) * 8;
    f32x4 s0v = {0,0,0,0}, s1v = {0,0,0,0};
#pragma unroll
    for (int w4 = 0; w4 < 4; w4++) {
        s0v += *reinterpret_cast<const f32x4*>(&comb[w4][i * 132 + c0]);
        s1v += *reinterpret_cast<const f32x4*>(&comb[w4][i * 132 + c0 + 4]);
    }
    f16x8 o;
#pragma unroll
    for (int e = 0; e < 4; e++) { o[e] = (f16)s0v[e]; o[4 + e] = (f16)s1v[e]; }
    *reinterpret_cast<f16x8*>(yT + ((size_t)bb * N_ + i0 + i) * CI + c0) = o;
}

// ---------------- pass 4: w_y = wz @ y + b, channel sums ----------------
__global__ __launch_bounds__(256) void k_wz(
        const f16* __restrict__ wzc, const f16* __restrict__ yT,
        const float* __restrict__ zb, float* __restrict__ wy,
        float* __restrict__ ssum, float* __restrict__ ssq) {
    int id = blockIdx.x;                  // 1024
    int nb = id & 63, ob = (id >> 6) & 3, bb = id >> 8;
    int t = threadIdx.x, w = t >> 6, l16 = t & 15, q = (t & 63) >> 4;
    int o0 = ob * 64 + w * 16, n0 = nb * 64;
    f32x4 acc[4] = {};
#pragma unroll
    for (int kk = 0; kk < 4; kk++) {
        f16x8 av = *reinterpret_cast<const f16x8*>(wzc + (o0 + l16) * CI + kk * 32 + q * 8);
#pragma unroll
        for (int nt = 0; nt < 4; nt++) {
            f16x8 bv = *reinterpret_cast<const f16x8*>(
                yT + ((size_t)bb * N_ + n0 + nt * 16 + l16) * CI + kk * 32 + q * 8);
            acc[nt] = MFMA(av, bv, acc[nt]);
        }
    }
#pragma unroll
    for (int r = 0; r < 4; r++) {
        int o = o0 + q * 4 + r;
        float bias = zb[o];
        float sr = 0.f, qr = 0.f;
#pragma unroll
        for (int nt = 0; nt < 4; nt++) {
            float v = acc[nt][r] + bias;
            wy[((size_t)bb * C_ + o) * N_ + n0 + nt * 16 + l16] = v;
            sr += v; qr += v * v;
        }
#pragma unroll
        for (int off = 1; off < 16; off <<= 1) {
            sr += __shfl_xor(sr, off);
            qr += __shfl_xor(qr, off);
        }
        if (l16 == 0) { atomicAdd(&ssum[o], sr); atomicAdd(&ssq[o], qr); }
    }
}

__global__ void k_bnprep(const float* ssum, const float* ssq, const float* gamma,
                         const float* beta, float* sc, float* sh) {
    int o = threadIdx.x;
    float inv = 1.0f / 16384.0f;
    float mean = ssum[o] * inv;
    float var = ssq[o] * inv - mean * mean;
    float s = gamma[o] * rsqrtf(var + 1e-5f);
    sc[o] = s;
    sh[o] = beta[o] - mean * s;
}

__global__ void k_final(const float* __restrict__ wy, const float* __restrict__ x,
                        const float* __restrict__ sc, const float* __restrict__ sh,
                        float* __restrict__ out) {
    int p = blockIdx.x * 256 + threadIdx.x;           // 1M float4s
    int c = (p >> 10) & 255;
    float4 wv = reinterpret_cast<const float4*>(wy)[p];
    float4 xv = reinterpret_cast<const float4*>(x)[p];
    float s = sc[c], h = sh[c];
    float4 o;
    o.x = wv.x * s + h + xv.x;
    o.y = wv.y * s + h + xv.y;
    o.z = wv.z * s + h + xv.z;
    o.w = wv.w * s + h + xv.w;
    reinterpret_cast<float4*>(out)[p] = o;
}

extern "C" void kernel_launch(void* const* d_in, const int* in_sizes, int n_in,
                              void* d_out, int out_size, void* d_ws, size_t ws_size,
                              hipStream_t stream) {
    const float* x     = (const float*)d_in[0];
    const float* gw    = (const float*)d_in[1];
    const float* gb    = (const float*)d_in[2];
    const float* tw    = (const float*)d_in[3];
    const float* tbv   = (const float*)d_in[4];
    const float* pw    = (const float*)d_in[5];
    const float* pb    = (const float*)d_in[6];
    const float* zw    = (const float*)d_in[7];
    const float* zb    = (const float*)d_in[8];
    const float* gamma = (const float*)d_in[9];
    const float* beta  = (const float*)d_in[10];

    char* ws = (char*)d_ws;
    f16* thetaT = (f16*)(ws + OFF_THETA);
    f16* phiT   = (f16*)(ws + OFF_PHI);
    f16* gC     = (f16*)(ws + OFF_G);
    f16* yT     = (f16*)(ws + OFF_Y);
    float* wy   = (float*)(ws + OFF_WY);
    f16* wcvt   = (f16*)(ws + OFF_WCVT);
    float* pm   = (float*)(ws + OFF_PM);
    float* ps   = (float*)(ws + OFF_PS);
    float* mcol = (float*)(ws + OFF_M);
    float* rdcol= (float*)(ws + OFF_RD);
    float* ssum = (float*)(ws + OFF_SSUM);
    float* ssq  = (float*)(ws + OFF_SSQ);
    float* sc   = (float*)(ws + OFF_SC);
    float* sh   = (float*)(ws + OFF_SH);

    hipMemsetAsync(ws + OFF_SSUM, 0, 2048, stream);   // zero ssum+ssq (ws is poisoned)

    k_prep<<<512, 256, 0, stream>>>(gw, tw, pw, zw, wcvt);
    k_proj<<<dim3(256, 3), 256, 0, stream>>>(x, wcvt, gb, tbv, pb, thetaT, phiT, gC);
    k_cols<<<2048, 64, 0, stream>>>(thetaT, phiT, pm, ps);
    k_colmerge<<<64, 256, 0, stream>>>(pm, ps, mcol, rdcol);
    k_attn<<<1024, 256, 0, stream>>>(thetaT, phiT, gC, mcol, rdcol, yT);
    k_wz<<<1024, 256, 0, stream>>>(wcvt + 3 * 32768, yT, zb, wy, ssum, ssq);
    k_bnprep<<<1, 256, 0, stream>>>(ssum, ssq, gamma, beta, sc, sh);
    k_final<<<4096, 256, 0, stream>>>(wy, x, sc, sh, (float*)d_out);
}

// Round 2
// 298.487 us; speedup vs baseline: 1.4739x; 1.4739x over previous
//
#include <hip/hip_runtime.h>

// NonLocalBlock: B=4, C=256, Ci=128, H=W=64, N=4096.
// f16 MFMA (16x16x32); f (4096x4096/batch) never materialized.
// R2: k_attn/k_cols rebuilt around LDS-staged j/i tiles with async
// global_load_lds (width 16) + XOR chunk swizzle (conflict-free, unpadded)
// + double buffering. Cache-side traffic 2GB -> ~0.6GB.

#define B_  4
#define C_  256
#define CI  128
#define N_  4096
#define NB  (B_*N_)     // 16384
#define ISPLIT 4

typedef _Float16 f16;
typedef f16   f16x8 __attribute__((ext_vector_type(8)));
typedef f16   f16x4 __attribute__((ext_vector_type(4)));
typedef float f32x4 __attribute__((ext_vector_type(4)));

#define MFMA(a,b,c) __builtin_amdgcn_mfma_f32_16x16x32_f16(a,b,c,0,0,0)

// async global->LDS, 16B per lane; LDS dest = wave-uniform base + lane*16
#define GLD16(g, lp) __builtin_amdgcn_global_load_lds( \
    (const __attribute__((address_space(1))) void*)(g), \
    (__attribute__((address_space(3))) void*)(lp), 16, 0, 0)

// ---- workspace byte offsets ----
#define OFF_THETA  0                       // f16 [B][N][CI]  4 MB
#define OFF_PHI    (4u<<20)                // f16 [B][N][CI]  4 MB
#define OFF_G      (8u<<20)                // f16 [B][CI][N]  4 MB
#define OFF_Y      (12u<<20)               // f16 [B][N][CI]  4 MB
#define OFF_WY     (16u<<20)               // f32 [B][C][N]  16 MB
#define OFF_WCVT   (32u<<20)               // f16 weights
#define OFF_PM     ((32u<<20) + (1u<<18))  // f32 [ISPLIT][NB]
#define OFF_PS     (OFF_PM + (ISPLIT*NB*4))
#define OFF_MR     (OFF_PS + (ISPLIT*NB*4))  // float2 [NB] (m, 1/D)
#define OFF_SSUM   (OFF_MR + NB*8)
#define OFF_SSQ    (OFF_SSUM + 1024)
#define OFF_SC     (OFF_SSQ + 1024)
#define OFF_SH     (OFF_SC + 1024)

// ---------------- weight conversion f32 -> f16 ----------------
__global__ void k_prep(const float* gw, const float* tw, const float* pw,
                       const float* zw, f16* wcvt) {
    int i = blockIdx.x * 256 + threadIdx.x;          // 0..131071
    const float* s;
    int which = i >> 15;
    if (which == 0) s = gw; else if (which == 1) s = tw;
    else if (which == 2) s = pw; else s = zw;
    wcvt[i] = (f16)s[i & 32767];
}

// ---------------- fused 1x1-conv projections (MFMA) ----------------
__global__ __launch_bounds__(256) void k_proj(
        const float* __restrict__ x, const f16* __restrict__ wcvt,
        const float* __restrict__ gb, const float* __restrict__ tb,
        const float* __restrict__ pb,
        f16* __restrict__ thetaT, f16* __restrict__ phiT, f16* __restrict__ gC) {
    __shared__ __align__(16) f16 xT[64 * 264];       // [n][c], stride 264
    int proj = blockIdx.y;
    int bb = blockIdx.x >> 6;
    int n0 = (blockIdx.x & 63) * 64;
    int t = threadIdx.x;

    const float* xb = x + (size_t)bb * C_ * N_;
    for (int rep = 0; rep < 16; rep++) {
        int lin = rep * 256 + t;
        int c = lin >> 4, np = (lin & 15) * 4;
        float4 v = *reinterpret_cast<const float4*>(xb + c * N_ + n0 + np);
        xT[(np + 0) * 264 + c] = (f16)v.x;
        xT[(np + 1) * 264 + c] = (f16)v.y;
        xT[(np + 2) * 264 + c] = (f16)v.z;
        xT[(np + 3) * 264 + c] = (f16)v.w;
    }
    __syncthreads();

    int w = t >> 6, l16 = t & 15, q = (t & 63) >> 4;
    const f16* W0 = wcvt + proj * 32768;             // [128][256] row-major
    int ci0 = w * 32;
    f32x4 acc[2][4] = {};
    for (int kk = 0; kk < 8; kk++) {
        f16x8 a0 = *reinterpret_cast<const f16x8*>(W0 + (ci0 + l16) * 256 + kk * 32 + q * 8);
        f16x8 a1 = *reinterpret_cast<const f16x8*>(W0 + (ci0 + 16 + l16) * 256 + kk * 32 + q * 8);
#pragma unroll
        for (int nt = 0; nt < 4; nt++) {
            f16x8 bv = *reinterpret_cast<const f16x8*>(&xT[(nt * 16 + l16) * 264 + kk * 32 + q * 8]);
            acc[0][nt] = MFMA(a0, bv, acc[0][nt]);
            acc[1][nt] = MFMA(a1, bv, acc[1][nt]);
        }
    }
    const float* bias = (proj == 0) ? gb : (proj == 1) ? tb : pb;
#pragma unroll
    for (int a = 0; a < 2; a++) {
#pragma unroll
        for (int nt = 0; nt < 4; nt++) {
            int n = n0 + nt * 16 + l16;
            int cib = ci0 + a * 16 + q * 4;
            if (proj == 0) {
#pragma unroll
                for (int r = 0; r < 4; r++)
                    gC[((size_t)bb * CI + cib + r) * N_ + n] = (f16)(acc[a][nt][r] + bias[cib + r]);
            } else {
                f16x4 v4;
#pragma unroll
                for (int r = 0; r < 4; r++) v4[r] = (f16)(acc[a][nt][r] + bias[cib + r]);
                f16* dst = (proj == 1 ? thetaT : phiT) + ((size_t)bb * N_ + n) * CI + cib;
                *reinterpret_cast<f16x4*>(dst) = v4;
            }
        }
    }
}

// ---------------- pass 2: column softmax stats ----------------
// block: bb x jb(256 j) x isp(1024 i). 4 waves x 64 j (phi frags in regs).
// theta staged in LDS i-tiles of 64 via async global_load_lds, double-buffered.
__global__ __launch_bounds__(256) void k_cols(
        const f16* __restrict__ thetaT, const f16* __restrict__ phiT,
        float* __restrict__ pm, float* __restrict__ ps) {
    __shared__ __align__(16) f16 thS[2][64 * 128];
    int id = blockIdx.x;                 // 256 = bb(4) x jb(16) x isp(4)
    int isp = id & 3, jb = (id >> 2) & 15, bb = id >> 6;
    int t = threadIdx.x, w = t >> 6, l = t & 63, l16 = t & 15, q = (t & 63) >> 4;
    int jw0 = jb * 256 + w * 64;

    f16x8 pf[4][4];
    const f16* pb = phiT + ((size_t)bb * N_ + jw0) * CI;
#pragma unroll
    for (int jt = 0; jt < 4; jt++)
#pragma unroll
        for (int kk = 0; kk < 4; kk++)
            pf[jt][kk] = *reinterpret_cast<const f16x8*>(pb + (jt * 16 + l16) * CI + kk * 32 + q * 8);

    const f16* thB = thetaT + ((size_t)bb * N_ + isp * 1024) * CI;
    auto stage = [&](int bf, int it0) {
#pragma unroll
        for (int r = 0; r < 4; r++) {
            int p = r * 256 + w * 64 + l;
            int pi = p >> 4, pu = (p & 15) ^ (pi & 15);
            const char* ga = (const char*)(thB + (size_t)(it0 + pi) * CI) + pu * 16;
            GLD16(ga, &thS[bf][(r * 256 + w * 64) * 8]);
        }
    };

    float m[4], s[4];
#pragma unroll
    for (int jt = 0; jt < 4; jt++) { m[jt] = -__builtin_inff(); s[jt] = 0.f; }

    stage(0, 0);
    __syncthreads();
    for (int it = 0; it < 16; it++) {
        int bf = it & 1;
        if (it + 1 < 16) stage(bf ^ 1, (it + 1) * 64);
#pragma unroll
        for (int ic = 0; ic < 4; ic++) {
            f16x8 av[4];
#pragma unroll
            for (int kk = 0; kk < 4; kk++)
                av[kk] = *reinterpret_cast<const f16x8*>(
                    &thS[bf][(ic * 16 + l16) * 128 + (((kk * 4 + q) ^ l16) * 8)]);
            f32x4 f[4] = {};
#pragma unroll
            for (int kk = 0; kk < 4; kk++)
#pragma unroll
                for (int jt = 0; jt < 4; jt++)
                    f[jt] = MFMA(av[kk], pf[jt][kk], f[jt]);
#pragma unroll
            for (int jt = 0; jt < 4; jt++) {
                float vm = fmaxf(fmaxf(f[jt][0], f[jt][1]), fmaxf(f[jt][2], f[jt][3]));
                float mn = fmaxf(m[jt], vm);
                s[jt] = s[jt] * __expf(m[jt] - mn)
                      + __expf(f[jt][0]-mn) + __expf(f[jt][1]-mn)
                      + __expf(f[jt][2]-mn) + __expf(f[jt][3]-mn);
                m[jt] = mn;
            }
        }
        __syncthreads();
    }
#pragma unroll
    for (int jt = 0; jt < 4; jt++) {
#pragma unroll
        for (int off = 16; off < 64; off <<= 1) {
            float om = __shfl_xor(m[jt], off), os = __shfl_xor(s[jt], off);
            float mn = fmaxf(m[jt], om);
            s[jt] = s[jt] * __expf(m[jt] - mn) + os * __expf(om - mn);
            m[jt] = mn;
        }
    }
    if (q == 0) {
#pragma unroll
        for (int jt = 0; jt < 4; jt++) {
            int base = isp * NB + bb * N_ + jw0 + jt * 16 + l16;
            pm[base] = m[jt]; ps[base] = s[jt];
        }
    }
}

__global__ void k_colmerge(const float* __restrict__ pm, const float* __restrict__ ps,
                           float2* __restrict__ mr) {
    int j = blockIdx.x * 256 + threadIdx.x;          // 0..16383
    float m = pm[j];
    for (int isp = 1; isp < ISPLIT; isp++) m = fmaxf(m, pm[isp * NB + j]);
    float s = 0.f;
    for (int isp = 0; isp < ISPLIT; isp++) s += ps[isp * NB + j] * __expf(pm[isp * NB + j] - m);
    mr[j] = make_float2(m, 1.0f / s);
}

// ---------------- pass 3: y = softmax(f) @ g ----------------
// block = 64 query rows (4 waves x 16 i), grid 256. j-tiles of 64 staged in LDS
// (phi 16KB + g 16KB, XOR-swizzled, async global_load_lds), double-buffered.
__global__ __launch_bounds__(256) void k_attn(
        const f16* __restrict__ thetaT, const f16* __restrict__ phiT,
        const f16* __restrict__ gC, const float2* __restrict__ mr,
        f16* __restrict__ yT) {
    __shared__ __align__(16) f16 phiS[2][64 * 128];   // [j][c] swizzled, 16KB ea
    __shared__ __align__(16) f16 gS[2][128 * 64];     // [c][j] swizzled, 16KB ea
    __shared__ __align__(16) f16 Wl[4][16 * 72];      // per-wave [i][j] pad->72
    __shared__ __align__(16) f16 yTr[4][16 * 136];    // per-wave [i][c] pad->136

    int bb = blockIdx.x >> 6;
    int i0 = (blockIdx.x & 63) * 64;
    int t = threadIdx.x, w = t >> 6, l = t & 63, l16 = t & 15, q = (t & 63) >> 4;

    f16x8 ta[4];
    const f16* tb = thetaT + ((size_t)bb * N_ + i0 + w * 16 + l16) * CI;
#pragma unroll
    for (int kk = 0; kk < 4; kk++)
        ta[kk] = *reinterpret_cast<const f16x8*>(tb + kk * 32 + q * 8);

    const f16* phiB = phiT + (size_t)bb * N_ * CI;
    const f16* gB   = gC   + (size_t)bb * CI * N_;
    const float2* mrb = mr + bb * N_;

    auto stage = [&](int bf, int j0g) {
#pragma unroll
        for (int r = 0; r < 4; r++) {
            int p = r * 256 + w * 64 + l;
            int ub = (r * 256 + w * 64) * 8;          // wave-uniform LDS base (f16)
            int pj = p >> 4, pu = (p & 15) ^ (pj & 15);
            const char* ga = (const char*)(phiB + (size_t)(j0g + pj) * CI) + pu * 16;
            GLD16(ga, &phiS[bf][ub]);
            int pc = p >> 3, pu2 = (p & 7) ^ (pc & 7);
            const char* ga2 = (const char*)(gB + (size_t)pc * N_ + j0g) + pu2 * 16;
            GLD16(ga2, &gS[bf][ub]);
        }
    };

    f32x4 yacc[8] = {};
    stage(0, 0);
    __syncthreads();
    for (int jt = 0; jt < 64; jt++) {
        int bf = jt & 1;
        if (jt + 1 < 64) stage(bf ^ 1, (jt + 1) * 64);
        int j0 = jt * 64;
        // f = theta . phi  -> exp((f-m)*1) * (1/D) -> Wl  (4 j-subtiles of 16)
#pragma unroll
        for (int js = 0; js < 4; js++) {
            f32x4 f = {0,0,0,0};
#pragma unroll
            for (int kk = 0; kk < 4; kk++) {
                f16x8 pv = *reinterpret_cast<const f16x8*>(
                    &phiS[bf][(js * 16 + l16) * 128 + (((kk * 4 + q) ^ l16) * 8)]);
                f = MFMA(ta[kk], pv, f);
            }
            float2 mv = mrb[j0 + js * 16 + l16];
#pragma unroll
            for (int r = 0; r < 4; r++)
                Wl[w][(q * 4 + r) * 72 + js * 16 + l16] = (f16)(__expf(f[r] - mv.x) * mv.y);
        }
        // PV: same-wave LDS RAW on Wl (compiler inserts lgkmcnt wait)
#pragma unroll
        for (int kj = 0; kj < 2; kj++) {
            f16x8 wf = *reinterpret_cast<const f16x8*>(&Wl[w][l16 * 72 + kj * 32 + q * 8]);
#pragma unroll
            for (int d = 0; d < 8; d++) {
                f16x8 gv = *reinterpret_cast<const f16x8*>(
                    &gS[bf][(d * 16 + l16) * 64 + (((kj * 4 + q) ^ (l16 & 7)) * 8)]);
                yacc[d] = MFMA(wf, gv, yacc[d]);
            }
        }
        __syncthreads();
    }
    // epilogue: per-wave transpose C-layout -> [i][c] via wave-private LDS
#pragma unroll
    for (int d = 0; d < 8; d++)
#pragma unroll
        for (int r = 0; r < 4; r++)
            yTr[w][(q * 4 + r) * 136 + d * 16 + l16] = (f16)yacc[d][r];
    f16* yo = yT + ((size_t)bb * N_ + i0 + w * 16) * CI;
#pragma unroll
    for (int rr = 0; rr < 4; rr++) {
        int idx = rr * 64 + l;
        int i = idx >> 4, u = idx & 15;
        *reinterpret_cast<f16x8*>(yo + i * CI + u * 8) =
            *reinterpret_cast<const f16x8*>(&yTr[w][i * 136 + u * 8]);
    }
}

// ---------------- pass 4: w_y = wz @ y + b, channel sums ----------------
__global__ __launch_bounds__(256) void k_wz(
        const f16* __restrict__ wzc, const f16* __restrict__ yT,
        const float* __restrict__ zb, float* __restrict__ wy,
        float* __restrict__ ssum, float* __restrict__ ssq) {
    int id = blockIdx.x;                  // 1024
    int nb = id & 63, ob = (id >> 6) & 3, bb = id >> 8;
    int t = threadIdx.x, w = t >> 6, l16 = t & 15, q = (t & 63) >> 4;
    int o0 = ob * 64 + w * 16, n0 = nb * 64;
    f32x4 acc[4] = {};
#pragma unroll
    for (int kk = 0; kk < 4; kk++) {
        f16x8 av = *reinterpret_cast<const f16x8*>(wzc + (o0 + l16) * CI + kk * 32 + q * 8);
#pragma unroll
        for (int nt = 0; nt < 4; nt++) {
            f16x8 bv = *reinterpret_cast<const f16x8*>(
                yT + ((size_t)bb * N_ + n0 + nt * 16 + l16) * CI + kk * 32 + q * 8);
            acc[nt] = MFMA(av, bv, acc[nt]);
        }
    }
#pragma unroll
    for (int r = 0; r < 4; r++) {
        int o = o0 + q * 4 + r;
        float bias = zb[o];
        float sr = 0.f, qr = 0.f;
#pragma unroll
        for (int nt = 0; nt < 4; nt++) {
            float v = acc[nt][r] + bias;
            wy[((size_t)bb * C_ + o) * N_ + n0 + nt * 16 + l16] = v;
            sr += v; qr += v * v;
        }
#pragma unroll
        for (int off = 1; off < 16; off <<= 1) {
            sr += __shfl_xor(sr, off);
            qr += __shfl_xor(qr, off);
        }
        if (l16 == 0) { atomicAdd(&ssum[o], sr); atomicAdd(&ssq[o], qr); }
    }
}

__global__ void k_bnprep(const float* ssum, const float* ssq, const float* gamma,
                         const float* beta, float* sc, float* sh) {
    int o = threadIdx.x;
    float inv = 1.0f / 16384.0f;
    float mean = ssum[o] * inv;
    float var = ssq[o] * inv - mean * mean;
    float s = gamma[o] * rsqrtf(var + 1e-5f);
    sc[o] = s;
    sh[o] = beta[o] - mean * s;
}

__global__ void k_final(const float* __restrict__ wy, const float* __restrict__ x,
                        const float* __restrict__ sc, const float* __restrict__ sh,
                        float* __restrict__ out) {
    int p = blockIdx.x * 256 + threadIdx.x;           // 1M float4s
    int c = (p >> 10) & 255;
    float4 wv = reinterpret_cast<const float4*>(wy)[p];
    float4 xv = reinterpret_cast<const float4*>(x)[p];
    float s = sc[c], h = sh[c];
    float4 o;
    o.x = wv.x * s + h + xv.x;
    o.y = wv.y * s + h + xv.y;
    o.z = wv.z * s + h + xv.z;
    o.w = wv.w * s + h + xv.w;
    reinterpret_cast<float4*>(out)[p] = o;
}

extern "C" void kernel_launch(void* const* d_in, const int* in_sizes, int n_in,
                              void* d_out, int out_size, void* d_ws, size_t ws_size,
                              hipStream_t stream) {
    const float* x     = (const float*)d_in[0];
    const float* gw    = (const float*)d_in[1];
    const float* gb    = (const float*)d_in[2];
    const float* tw    = (const float*)d_in[3];
    const float* tbv   = (const float*)d_in[4];
    const float* pw    = (const float*)d_in[5];
    const float* pb    = (const float*)d_in[6];
    const float* zw    = (const float*)d_in[7];
    const float* zb    = (const float*)d_in[8];
    const float* gamma = (const float*)d_in[9];
    const float* beta  = (const float*)d_in[10];

    char* ws = (char*)d_ws;
    f16* thetaT = (f16*)(ws + OFF_THETA);
    f16* phiT   = (f16*)(ws + OFF_PHI);
    f16* gC     = (f16*)(ws + OFF_G);
    f16* yT     = (f16*)(ws + OFF_Y);
    float* wy   = (float*)(ws + OFF_WY);
    f16* wcvt   = (f16*)(ws + OFF_WCVT);
    float* pm   = (float*)(ws + OFF_PM);
    float* ps   = (float*)(ws + OFF_PS);
    float2* mr  = (float2*)(ws + OFF_MR);
    float* ssum = (float*)(ws + OFF_SSUM);
    float* ssq  = (float*)(ws + OFF_SSQ);
    float* sc   = (float*)(ws + OFF_SC);
    float* sh   = (float*)(ws + OFF_SH);

    hipMemsetAsync(ws + OFF_SSUM, 0, 2048, stream);   // zero ssum+ssq

    k_prep<<<512, 256, 0, stream>>>(gw, tw, pw, zw, wcvt);
    k_proj<<<dim3(256, 3), 256, 0, stream>>>(x, wcvt, gb, tbv, pb, thetaT, phiT, gC);
    k_cols<<<256, 256, 0, stream>>>(thetaT, phiT, pm, ps);
    k_colmerge<<<64, 256, 0, stream>>>(pm, ps, mr);
    k_attn<<<256, 256, 0, stream>>>(thetaT, phiT, gC, mr, yT);
    k_wz<<<1024, 256, 0, stream>>>(wcvt + 3 * 32768, yT, zb, wy, ssum, ssq);
    k_bnprep<<<1, 256, 0, stream>>>(ssum, ssq, gamma, beta, sc, sh);
    k_final<<<4096, 256, 0, stream>>>(wy, x, sc, sh, (float*)d_out);
}

// Round 4
// 238.982 us; speedup vs baseline: 1.8409x; 1.2490x over previous
//
#include <hip/hip_runtime.h>

// NonLocalBlock: B=4, C=256, Ci=128, H=W=64, N=4096.
// R4 = R3 with k_final grid fixed (2048, was 8192 -> OOB fault).
// k_attn: 32 i/wave + 4-way j-split -> 2 blocks/CU (LDS 73KB);
// k_cols ISPLIT=8; k_proj merged (x read once); wy stored f16 overlaying
// dead theta/phi region.

#define B_  4
#define C_  256
#define CI  128
#define N_  4096
#define NB  (B_*N_)     // 16384
#define ISPLIT 8
#define MB_ (1u<<20)

typedef _Float16 f16;
typedef f16   f16x8 __attribute__((ext_vector_type(8)));
typedef f16   f16x4 __attribute__((ext_vector_type(4)));
typedef float f32x4 __attribute__((ext_vector_type(4)));

#define MFMA(a,b,c) __builtin_amdgcn_mfma_f32_16x16x32_f16(a,b,c,0,0,0)

// async global->LDS, 16B per lane; LDS dest = wave-uniform base + lane*16
#define GLD16(g, lp) __builtin_amdgcn_global_load_lds( \
    (const __attribute__((address_space(1))) void*)(g), \
    (__attribute__((address_space(3))) void*)(lp), 16, 0, 0)

// ---- workspace byte offsets (~29.6 MB) ----
#define OFF_THETA  0                 // f16 [B][N][CI]  4 MB
#define OFF_PHI    (4u*MB_)          // f16 [B][N][CI]  4 MB
#define OFF_G      (8u*MB_)          // f16 [B][CI][N]  4 MB
#define OFF_YP     (12u*MB_)         // f16 [4][B][N][CI]  16 MB (j-quarter partials)
#define OFF_WY     0                 // f16 [B][C][N] 8 MB — overlays theta+phi (dead by k_wz)
#define OFF_WCVT   (28u*MB_)         // f16 weights 256 KB
#define OFF_PM     (28u*MB_ + (1u<<18))
#define OFF_PS     (OFF_PM + ISPLIT*NB*4)
#define OFF_MR     (OFF_PS + ISPLIT*NB*4)   // float2 [NB] (m, 1/D)
#define OFF_SSUM   (OFF_MR + NB*8)
#define OFF_SSQ    (OFF_SSUM + 1024)
#define OFF_SC     (OFF_SSQ + 1024)
#define OFF_SH     (OFF_SC + 1024)
#define PSZ ((size_t)B_*N_*CI)

// ---------------- weight conversion f32 -> f16 ----------------
__global__ void k_prep(const float* gw, const float* tw, const float* pw,
                       const float* zw, f16* wcvt) {
    int i = blockIdx.x * 256 + threadIdx.x;          // 0..131071
    const float* s;
    int which = i >> 15;
    if (which == 0) s = gw; else if (which == 1) s = tw;
    else if (which == 2) s = pw; else s = zw;
    wcvt[i] = (f16)s[i & 32767];
}

// ---------------- fused 1x1-conv projections (all 3, one x read) ----------------
__global__ __launch_bounds__(256) void k_proj(
        const float* __restrict__ x, const f16* __restrict__ wcvt,
        const float* __restrict__ gb, const float* __restrict__ tb,
        const float* __restrict__ pb,
        f16* __restrict__ thetaT, f16* __restrict__ phiT, f16* __restrict__ gC) {
    __shared__ __align__(16) f16 xT[64 * 264];       // [n][c], stride 264
    int bb = blockIdx.x >> 6;
    int n0 = (blockIdx.x & 63) * 64;
    int t = threadIdx.x;

    const float* xb = x + (size_t)bb * C_ * N_;
    for (int rep = 0; rep < 16; rep++) {
        int lin = rep * 256 + t;
        int c = lin >> 4, np = (lin & 15) * 4;
        float4 v = *reinterpret_cast<const float4*>(xb + c * N_ + n0 + np);
        xT[(np + 0) * 264 + c] = (f16)v.x;
        xT[(np + 1) * 264 + c] = (f16)v.y;
        xT[(np + 2) * 264 + c] = (f16)v.z;
        xT[(np + 3) * 264 + c] = (f16)v.w;
    }
    __syncthreads();

    int w = t >> 6, l16 = t & 15, q = (t & 63) >> 4;
    int ci0 = w * 32;
    for (int proj = 0; proj < 3; proj++) {
        const f16* W0 = wcvt + proj * 32768;         // [128][256] row-major
        f32x4 acc[2][4] = {};
        for (int kk = 0; kk < 8; kk++) {
            f16x8 a0 = *reinterpret_cast<const f16x8*>(W0 + (ci0 + l16) * 256 + kk * 32 + q * 8);
            f16x8 a1 = *reinterpret_cast<const f16x8*>(W0 + (ci0 + 16 + l16) * 256 + kk * 32 + q * 8);
#pragma unroll
            for (int nt = 0; nt < 4; nt++) {
                f16x8 bv = *reinterpret_cast<const f16x8*>(&xT[(nt * 16 + l16) * 264 + kk * 32 + q * 8]);
                acc[0][nt] = MFMA(a0, bv, acc[0][nt]);
                acc[1][nt] = MFMA(a1, bv, acc[1][nt]);
            }
        }
        const float* bias = (proj == 0) ? gb : (proj == 1) ? tb : pb;
#pragma unroll
        for (int a = 0; a < 2; a++) {
#pragma unroll
            for (int nt = 0; nt < 4; nt++) {
                int n = n0 + nt * 16 + l16;
                int cib = ci0 + a * 16 + q * 4;
                if (proj == 0) {
#pragma unroll
                    for (int r = 0; r < 4; r++)
                        gC[((size_t)bb * CI + cib + r) * N_ + n] = (f16)(acc[a][nt][r] + bias[cib + r]);
                } else {
                    f16x4 v4;
#pragma unroll
                    for (int r = 0; r < 4; r++) v4[r] = (f16)(acc[a][nt][r] + bias[cib + r]);
                    f16* dst = (proj == 1 ? thetaT : phiT) + ((size_t)bb * N_ + n) * CI + cib;
                    *reinterpret_cast<f16x4*>(dst) = v4;
                }
            }
        }
    }
}

// ---------------- pass 2: column softmax stats ----------------
// block: bb x jb(256 j) x isp(512 i). 4 waves x 64 j (phi frags in regs).
__global__ __launch_bounds__(256, 2) void k_cols(
        const f16* __restrict__ thetaT, const f16* __restrict__ phiT,
        float* __restrict__ pm, float* __restrict__ ps) {
    __shared__ __align__(16) f16 thS[2][64 * 128];
    int id = blockIdx.x;                 // 512 = bb(4) x jb(16) x isp(8)
    int isp = id & 7, jb = (id >> 3) & 15, bb = id >> 7;
    int t = threadIdx.x, w = t >> 6, l = t & 63, l16 = t & 15, q = (t & 63) >> 4;
    int jw0 = jb * 256 + w * 64;

    f16x8 pf[4][4];
    const f16* pb = phiT + ((size_t)bb * N_ + jw0) * CI;
#pragma unroll
    for (int jt = 0; jt < 4; jt++)
#pragma unroll
        for (int kk = 0; kk < 4; kk++)
            pf[jt][kk] = *reinterpret_cast<const f16x8*>(pb + (jt * 16 + l16) * CI + kk * 32 + q * 8);

    const f16* thB = thetaT + ((size_t)bb * N_ + isp * 512) * CI;
    auto stage = [&](int bf, int it0) {
#pragma unroll
        for (int r = 0; r < 4; r++) {
            int p = r * 256 + w * 64 + l;
            int pi = p >> 4, pu = (p & 15) ^ (pi & 15);
            const char* ga = (const char*)(thB + (size_t)(it0 + pi) * CI) + pu * 16;
            GLD16(ga, &thS[bf][(r * 256 + w * 64) * 8]);
        }
    };

    float m[4], s[4];
#pragma unroll
    for (int jt = 0; jt < 4; jt++) { m[jt] = -__builtin_inff(); s[jt] = 0.f; }

    stage(0, 0);
    __syncthreads();
    for (int it = 0; it < 8; it++) {
        int bf = it & 1;
        if (it + 1 < 8) stage(bf ^ 1, (it + 1) * 64);
#pragma unroll
        for (int ic = 0; ic < 4; ic++) {
            f16x8 av[4];
#pragma unroll
            for (int kk = 0; kk < 4; kk++)
                av[kk] = *reinterpret_cast<const f16x8*>(
                    &thS[bf][(ic * 16 + l16) * 128 + (((kk * 4 + q) ^ l16) * 8)]);
            f32x4 f[4] = {};
#pragma unroll
            for (int kk = 0; kk < 4; kk++)
#pragma unroll
                for (int jt = 0; jt < 4; jt++)
                    f[jt] = MFMA(av[kk], pf[jt][kk], f[jt]);
#pragma unroll
            for (int jt = 0; jt < 4; jt++) {
                float vm = fmaxf(fmaxf(f[jt][0], f[jt][1]), fmaxf(f[jt][2], f[jt][3]));
                float mn = fmaxf(m[jt], vm);
                s[jt] = s[jt] * __expf(m[jt] - mn)
                      + __expf(f[jt][0]-mn) + __expf(f[jt][1]-mn)
                      + __expf(f[jt][2]-mn) + __expf(f[jt][3]-mn);
                m[jt] = mn;
            }
        }
        __syncthreads();
    }
#pragma unroll
    for (int jt = 0; jt < 4; jt++) {
#pragma unroll
        for (int off = 16; off < 64; off <<= 1) {
            float om = __shfl_xor(m[jt], off), os = __shfl_xor(s[jt], off);
            float mn = fmaxf(m[jt], om);
            s[jt] = s[jt] * __expf(m[jt] - mn) + os * __expf(om - mn);
            m[jt] = mn;
        }
    }
    if (q == 0) {
#pragma unroll
        for (int jt = 0; jt < 4; jt++) {
            int base = isp * NB + bb * N_ + jw0 + jt * 16 + l16;
            pm[base] = m[jt]; ps[base] = s[jt];
        }
    }
}

__global__ void k_colmerge(const float* __restrict__ pm, const float* __restrict__ ps,
                           float2* __restrict__ mr) {
    int j = blockIdx.x * 256 + threadIdx.x;          // 0..16383
    float m = pm[j];
    for (int isp = 1; isp < ISPLIT; isp++) m = fmaxf(m, pm[isp * NB + j]);
    float s = 0.f;
    for (int isp = 0; isp < ISPLIT; isp++) s += ps[isp * NB + j] * __expf(pm[isp * NB + j] - m);
    mr[j] = make_float2(m, 1.0f / s);
}

// ---------------- pass 3: y = softmax(f) @ g ----------------
// block = 128 i (4 waves x 32 i), 4-way j-split (1024 j each), grid 512.
// j-tiles of 64 staged in LDS (phi+g, XOR-swizzled, async), double-buffered.
// Partial y (f16) per j-quarter; summed in k_wz.
__global__ __launch_bounds__(256, 2) void k_attn(
        const f16* __restrict__ thetaT, const f16* __restrict__ phiT,
        const f16* __restrict__ gC, const float2* __restrict__ mr,
        f16* __restrict__ yP) {
    __shared__ __align__(16) char smem[74752];
    f16 (*phiS)[64 * 128] = (f16(*)[64 * 128])smem;            // 2 x 16 KB
    f16 (*gS)[128 * 64]   = (f16(*)[128 * 64])(smem + 32768);  // 2 x 16 KB
    f16* Wl  = (f16*)(smem + 65536);                           // 4 x [32][36] = 9 KB
    f16* yTr = (f16*)smem;                                     // epilogue overlay

    int jq = blockIdx.x & 3;
    int ib = blockIdx.x >> 2;          // 0..127
    int bb = ib >> 5;
    int i0 = (ib & 31) * 128;
    int t = threadIdx.x, w = t >> 6, l = t & 63, l16 = t & 15, q = (t & 63) >> 4;
    int jbase = jq * 1024;

    f16x8 ta[2][4];
    const f16* tb = thetaT + ((size_t)bb * N_ + i0 + w * 32 + l16) * CI;
#pragma unroll
    for (int s = 0; s < 2; s++)
#pragma unroll
        for (int kk = 0; kk < 4; kk++)
            ta[s][kk] = *reinterpret_cast<const f16x8*>(tb + s * 16 * CI + kk * 32 + q * 8);

    const f16* phiB = phiT + (size_t)bb * N_ * CI;
    const f16* gB   = gC   + (size_t)bb * CI * N_;
    const float2* mrb = mr + bb * N_;

    auto stage = [&](int bf, int j0g) {
#pragma unroll
        for (int r = 0; r < 4; r++) {
            int p = r * 256 + w * 64 + l;
            int ub = (r * 256 + w * 64) * 8;          // wave-uniform LDS base (f16)
            int pj = p >> 4, pu = (p & 15) ^ (pj & 15);
            const char* ga = (const char*)(phiB + (size_t)(j0g + pj) * CI) + pu * 16;
            GLD16(ga, &phiS[bf][ub]);
            int pc = p >> 3, pu2 = (p & 7) ^ (pc & 7);
            const char* ga2 = (const char*)(gB + (size_t)pc * N_ + j0g) + pu2 * 16;
            GLD16(ga2, &gS[bf][ub]);
        }
    };

    f32x4 yacc[2][8] = {};
    f16* Wlw = Wl + w * (32 * 36);
    stage(0, jbase);
    __syncthreads();
    for (int jt = 0; jt < 16; jt++) {
        int bf = jt & 1;
        if (jt + 1 < 16) stage(bf ^ 1, jbase + (jt + 1) * 64);
#pragma unroll
        for (int jh = 0; jh < 2; jh++) {
            // f-phase: two 16-j subtiles of this 32-j half
#pragma unroll
            for (int js2 = 0; js2 < 2; js2++) {
                int js = jh * 2 + js2;
                f32x4 f0 = {0,0,0,0}, f1 = {0,0,0,0};
#pragma unroll
                for (int kk = 0; kk < 4; kk++) {
                    f16x8 pv = *reinterpret_cast<const f16x8*>(
                        &phiS[bf][(js * 16 + l16) * 128 + (((kk * 4 + q) ^ l16) * 8)]);
                    f0 = MFMA(ta[0][kk], pv, f0);
                    f1 = MFMA(ta[1][kk], pv, f1);
                }
                float2 mv = mrb[jbase + jt * 64 + js * 16 + l16];
#pragma unroll
                for (int r = 0; r < 4; r++) {
                    Wlw[(q * 4 + r) * 36 + js2 * 16 + l16]        = (f16)(__expf(f0[r] - mv.x) * mv.y);
                    Wlw[(16 + q * 4 + r) * 36 + js2 * 16 + l16]   = (f16)(__expf(f1[r] - mv.x) * mv.y);
                }
            }
            // PV over this 32-j half (same-wave LDS RAW: in-order DS ops)
            f16x8 wf0 = *reinterpret_cast<const f16x8*>(&Wlw[l16 * 36 + q * 8]);
            f16x8 wf1 = *reinterpret_cast<const f16x8*>(&Wlw[(16 + l16) * 36 + q * 8]);
#pragma unroll
            for (int d = 0; d < 8; d++) {
                f16x8 gv = *reinterpret_cast<const f16x8*>(
                    &gS[bf][(d * 16 + l16) * 64 + (((jh * 4 + q) ^ (l16 & 7)) * 8)]);
                yacc[0][d] = MFMA(wf0, gv, yacc[0][d]);
                yacc[1][d] = MFMA(wf1, gv, yacc[1][d]);
            }
        }
        __syncthreads();
    }
    // epilogue: per-wave transpose C-layout -> [i][c], write f16 partial
    f16* yw = yTr + w * (32 * 136);
#pragma unroll
    for (int s = 0; s < 2; s++)
#pragma unroll
        for (int d = 0; d < 8; d++)
#pragma unroll
            for (int r = 0; r < 4; r++)
                yw[(s * 16 + q * 4 + r) * 136 + d * 16 + l16] = (f16)yacc[s][d][r];
    f16* yo = yP + (size_t)jq * PSZ + ((size_t)bb * N_ + i0 + w * 32) * CI;
#pragma unroll
    for (int rr = 0; rr < 8; rr++) {
        int chunk = rr * 64 + l;
        int il = chunk >> 4, u = chunk & 15;
        *reinterpret_cast<f16x8*>(yo + il * CI + u * 8) =
            *reinterpret_cast<const f16x8*>(&yw[il * 136 + u * 8]);
    }
}

// ---------------- pass 4: w_y = wz @ (sum of y partials) + b, channel sums ----------------
__global__ __launch_bounds__(256) void k_wz(
        const f16* __restrict__ wzc, const f16* __restrict__ yP,
        const float* __restrict__ zb, f16* __restrict__ wy,
        float* __restrict__ ssum, float* __restrict__ ssq) {
    int id = blockIdx.x;                  // 1024
    int nb = id & 63, ob = (id >> 6) & 3, bb = id >> 8;
    int t = threadIdx.x, w = t >> 6, l16 = t & 15, q = (t & 63) >> 4;
    int o0 = ob * 64 + w * 16, n0 = nb * 64;
    f32x4 acc[4] = {};
#pragma unroll
    for (int kk = 0; kk < 4; kk++) {
        f16x8 av = *reinterpret_cast<const f16x8*>(wzc + (o0 + l16) * CI + kk * 32 + q * 8);
#pragma unroll
        for (int nt = 0; nt < 4; nt++) {
            size_t yi = ((size_t)bb * N_ + n0 + nt * 16 + l16) * CI + kk * 32 + q * 8;
            f16x8 b0 = *reinterpret_cast<const f16x8*>(yP + yi);
            f16x8 b1 = *reinterpret_cast<const f16x8*>(yP + PSZ + yi);
            f16x8 b2 = *reinterpret_cast<const f16x8*>(yP + 2 * PSZ + yi);
            f16x8 b3 = *reinterpret_cast<const f16x8*>(yP + 3 * PSZ + yi);
            f16x8 bv = (b0 + b1) + (b2 + b3);
            acc[nt] = MFMA(av, bv, acc[nt]);
        }
    }
#pragma unroll
    for (int r = 0; r < 4; r++) {
        int o = o0 + q * 4 + r;
        float bias = zb[o];
        float sr = 0.f, qr = 0.f;
#pragma unroll
        for (int nt = 0; nt < 4; nt++) {
            float v = acc[nt][r] + bias;
            wy[((size_t)bb * C_ + o) * N_ + n0 + nt * 16 + l16] = (f16)v;
            sr += v; qr += v * v;
        }
#pragma unroll
        for (int off = 1; off < 16; off <<= 1) {
            sr += __shfl_xor(sr, off);
            qr += __shfl_xor(qr, off);
        }
        if (l16 == 0) { atomicAdd(&ssum[o], sr); atomicAdd(&ssq[o], qr); }
    }
}

__global__ void k_bnprep(const float* ssum, const float* ssq, const float* gamma,
                         const float* beta, float* sc, float* sh) {
    int o = threadIdx.x;
    float inv = 1.0f / 16384.0f;
    float mean = ssum[o] * inv;
    float var = ssq[o] * inv - mean * mean;
    float s = gamma[o] * rsqrtf(var + 1e-5f);
    sc[o] = s;
    sh[o] = beta[o] - mean * s;
}

__global__ void k_final(const f16* __restrict__ wy, const float* __restrict__ x,
                        const float* __restrict__ sc, const float* __restrict__ sh,
                        float* __restrict__ out) {
    int p = blockIdx.x * 256 + threadIdx.x;           // 512K groups of 8
    int c = (p >> 9) & 255;
    f16x8 wv = reinterpret_cast<const f16x8*>(wy)[p];
    float4 x0 = reinterpret_cast<const float4*>(x)[2 * p];
    float4 x1 = reinterpret_cast<const float4*>(x)[2 * p + 1];
    float s = sc[c], h = sh[c];
    float4 o0, o1;
    o0.x = (float)wv[0] * s + h + x0.x;
    o0.y = (float)wv[1] * s + h + x0.y;
    o0.z = (float)wv[2] * s + h + x0.z;
    o0.w = (float)wv[3] * s + h + x0.w;
    o1.x = (float)wv[4] * s + h + x1.x;
    o1.y = (float)wv[5] * s + h + x1.y;
    o1.z = (float)wv[6] * s + h + x1.z;
    o1.w = (float)wv[7] * s + h + x1.w;
    reinterpret_cast<float4*>(out)[2 * p] = o0;
    reinterpret_cast<float4*>(out)[2 * p + 1] = o1;
}

extern "C" void kernel_launch(void* const* d_in, const int* in_sizes, int n_in,
                              void* d_out, int out_size, void* d_ws, size_t ws_size,
                              hipStream_t stream) {
    const float* x     = (const float*)d_in[0];
    const float* gw    = (const float*)d_in[1];
    const float* gb    = (const float*)d_in[2];
    const float* tw    = (const float*)d_in[3];
    const float* tbv   = (const float*)d_in[4];
    const float* pw    = (const float*)d_in[5];
    const float* pb    = (const float*)d_in[6];
    const float* zw    = (const float*)d_in[7];
    const float* zb    = (const float*)d_in[8];
    const float* gamma = (const float*)d_in[9];
    const float* beta  = (const float*)d_in[10];

    char* ws = (char*)d_ws;
    f16* thetaT = (f16*)(ws + OFF_THETA);
    f16* phiT   = (f16*)(ws + OFF_PHI);
    f16* gC     = (f16*)(ws + OFF_G);
    f16* yP     = (f16*)(ws + OFF_YP);
    f16* wy     = (f16*)(ws + OFF_WY);
    f16* wcvt   = (f16*)(ws + OFF_WCVT);
    float* pm   = (float*)(ws + OFF_PM);
    float* ps   = (float*)(ws + OFF_PS);
    float2* mr  = (float2*)(ws + OFF_MR);
    float* ssum = (float*)(ws + OFF_SSUM);
    float* ssq  = (float*)(ws + OFF_SSQ);
    float* sc   = (float*)(ws + OFF_SC);
    float* sh   = (float*)(ws + OFF_SH);

    hipMemsetAsync(ws + OFF_SSUM, 0, 2048, stream);   // zero ssum+ssq

    k_prep<<<512, 256, 0, stream>>>(gw, tw, pw, zw, wcvt);
    k_proj<<<256, 256, 0, stream>>>(x, wcvt, gb, tbv, pb, thetaT, phiT, gC);
    k_cols<<<512, 256, 0, stream>>>(thetaT, phiT, pm, ps);
    k_colmerge<<<64, 256, 0, stream>>>(pm, ps, mr);
    k_attn<<<512, 256, 0, stream>>>(thetaT, phiT, gC, mr, yP);
    k_wz<<<1024, 256, 0, stream>>>(wcvt + 3 * 32768, yP, zb, wy, ssum, ssq);
    k_bnprep<<<1, 256, 0, stream>>>(ssum, ssq, gamma, beta, sc, sh);
    // B*C*N/8 = 524288 f16x8 groups / 256 threads = 2048 blocks (8192 was the R3 OOB fault)
    k_final<<<2048, 256, 0, stream>>>(wy, x, sc, sh, (float*)d_out);
}